// Round 14
// baseline (348.954 us; speedup 1.0000x reference)
//
#include <hip/hip_runtime.h>
#include <cstdint>
#include <cstddef>

#define NB 8
#define CIN 256
#define HWX 4096
#define CF 256
#define CA 128
#define CT 384

typedef __attribute__((ext_vector_type(8))) _Float16 half8;
typedef __attribute__((ext_vector_type(8))) short short8;
typedef __attribute__((ext_vector_type(4))) short s16x4;
typedef __attribute__((ext_vector_type(4))) float f32x4;
typedef __attribute__((ext_vector_type(4))) unsigned int u32x4;
typedef __attribute__((ext_vector_type(2))) unsigned int u32x2;

// workspace layout (bytes)
#define OFF_WH   0                              // 384*256 fp16 folded weights
#define OFF_BIAS (CT*CIN*2)                     // 384 fp32 folded bias
#define OFF_FEAT (OFF_BIAS + CT*4)              // [n][256][4096] fp16
#define OFF_Q    (OFF_FEAT + NB*CF*HWX*2)       // [n][4096][128] fp16
#define OFF_NORM (OFF_Q + NB*HWX*CA*2)          // [n][4096] fp32 row norms of q
#define OFF_G    (OFF_NORM + NB*HWX*4)          // [n] uint (max norm bits)

__device__ inline unsigned short f16_bits(float f) {
  _Float16 h = (_Float16)f;
  return __builtin_bit_cast(unsigned short, h);
}
__device__ inline half8 ld_half8(const unsigned short* p) {
  short8 r = *(const short8*)p;
  return __builtin_bit_cast(half8, r);
}

// async global->LDS, 16B per lane; LDS side must be lane-linear (m104/m108),
// swizzle goes on the GLOBAL address.
__device__ inline void g2l16(const void* g, void* l) {
  __builtin_amdgcn_global_load_lds(
      (const __attribute__((address_space(1))) unsigned int*)g,
      (__attribute__((address_space(3))) unsigned int*)l, 16, 0, 0);
}

// ---------------- kernel 1: fold BN into fp16 weights (+ zero G) ----------------
__global__ __launch_bounds__(256) void fold_bn_k(
    const float* __restrict__ rw, const float* __restrict__ rg,
    const float* __restrict__ rb, const float* __restrict__ rm, const float* __restrict__ rv,
    const float* __restrict__ aw, const float* __restrict__ ag,
    const float* __restrict__ ab2, const float* __restrict__ am, const float* __restrict__ av,
    unsigned short* __restrict__ wh, float* __restrict__ bias, unsigned* __restrict__ Gmax) {
  int o = blockIdx.x, k = threadIdx.x;
  if (o == 0 && k < NB) Gmax[k] = 0u;
  const float* wsrc; float g, b, m, v;
  if (o < CF) { wsrc = rw + (size_t)o*CIN; g = rg[o]; b = rb[o]; m = rm[o]; v = rv[o]; }
  else { int oa = o - CF; wsrc = aw + (size_t)oa*CIN; g = ag[oa]; b = ab2[oa]; m = am[oa]; v = av[oa]; }
  float inv = g / sqrtf(v + 1e-5f);
  wh[(size_t)o*CIN + k] = f16_bits(wsrc[k] * inv);
  if (k == 0) bias[o] = b - m*inv;
}

// ---------------- kernel 2: fp16 MFMA conv(1x1)+BN+ReLU, 64-pos tiles ----------------
// EXACT R11 conv (banked best: residual 93-98us). R10 tile-halving (+8us) and R12
// oc-split occupancy (null) both exonerated occupancy as the conv limiter.
// grid 512 = 8n x 64 pos-tiles(64); 512 thr; 2 blocks/CU.
// B3 register-prefetch (R3, real); 1 atomic/block (R6, real: 111->93).
__global__ __launch_bounds__(512, 4) void conv_k(
    const float* __restrict__ x, const unsigned short* __restrict__ wh,
    const float* __restrict__ bias, unsigned short* __restrict__ feat,
    unsigned short* __restrict__ q, float* __restrict__ normq,
    unsigned* __restrict__ Gmax) {
  __shared__ unsigned short sX[64*256];   // xT [64 pos][256 k] fp16, swizzled; 32KB
  __shared__ float sGm[4];
  unsigned short (*sQr)[136] = (unsigned short(*)[136])sX;  // aliased after K-loop
  int b = blockIdx.x;
  int n = b & 7, pt0 = b >> 3;
  int p0 = pt0 * 64;
  int t = threadIdx.x;
  int w = t >> 6, lane = t & 63, quad = lane >> 4, col = lane & 15;
  const float* xn = x + (size_t)n*CIN*HWX;

  #pragma unroll
  for (int pass=0; pass<4; pass++) {
    int idx = pass*512 + t;
    int kp = idx >> 4, c4 = idx & 15;
    f32x4 a = *(const f32x4*)(xn + (size_t)(2*kp)*HWX + p0 + c4*4);
    f32x4 c = *(const f32x4*)(xn + (size_t)(2*kp+1)*HWX + p0 + c4*4);
    int unit = kp >> 2, off = kp & 3;
    #pragma unroll
    for (int j=0;j<4;j++) {
      int pos = c4*4 + j;
      unsigned dd = (unsigned)f16_bits(a[j]) | ((unsigned)f16_bits(c[j]) << 16);
      *(unsigned*)&sX[pos*256 + ((unit ^ (pos & 31)) << 3) + off*2] = dd;
    }
  }
  __syncthreads();

  f32x4 fzero = {0.f,0.f,0.f,0.f};
  f32x4 acc[4][3];
  #pragma unroll
  for (int pt=0;pt<4;pt++)
    #pragma unroll
    for (int ot=0;ot<3;ot++) acc[pt][ot] = fzero;

  int ocb = w*48;
  half8 B3[3];
  #pragma unroll
  for (int ot=0;ot<3;ot++)
    B3[ot] = ld_half8(wh + (size_t)(ocb + ot*16 + col)*CIN + quad*8);   // ks=0
  #pragma unroll
  for (int ks=0; ks<8; ks++) {
    half8 B3n[3];
    if (ks < 7) {
      #pragma unroll
      for (int ot=0;ot<3;ot++)
        B3n[ot] = ld_half8(wh + (size_t)(ocb + ot*16 + col)*CIN + (ks+1)*32 + quad*8);
    }
    half8 A4[4];
    #pragma unroll
    for (int pt=0;pt<4;pt++) {
      int pos = pt*16 + col;
      A4[pt] = ld_half8(&sX[pos*256 + (((ks*4 + quad) ^ (pos & 31)) << 3)]);
    }
    #pragma unroll
    for (int pt=0;pt<4;pt++)
      #pragma unroll
      for (int ot=0;ot<3;ot++)
        acc[pt][ot] = __builtin_amdgcn_mfma_f32_16x16x32_f16(A4[pt], B3[ot], acc[pt][ot], 0, 0, 0);
    if (ks < 7) {
      #pragma unroll
      for (int ot=0;ot<3;ot++) B3[ot] = B3n[ot];
    }
  }
  __syncthreads();   // all sX reads done; region reused as sQr

  float bv[3];
  #pragma unroll
  for (int ot=0;ot<3;ot++) bv[ot] = bias[ocb + ot*16 + col];
  #pragma unroll
  for (int pt=0;pt<4;pt++)
    #pragma unroll
    for (int ot=0;ot<3;ot++) {
      int oc = ocb + ot*16 + col;
      alignas(8) unsigned short u4[4];
      #pragma unroll
      for (int r=0;r<4;r++)
        u4[r] = f16_bits(fmaxf(acc[pt][ot][r] + bv[ot], 0.f));
      if (oc < CF) {
        *(u32x2*)(feat + (size_t)n*CF*HWX + (size_t)oc*HWX + p0 + pt*16 + quad*4) =
            *(const u32x2*)u4;
      } else {
        int cc = oc - CF;
        #pragma unroll
        for (int r=0;r<4;r++)
          sQr[pt*16 + quad*4 + r][cc] = u4[r];
      }
    }
  __syncthreads();

  if (t < 256) {
    int pos = t >> 2, seg = t & 3;
    const unsigned short* src = &sQr[pos][seg*32];
    unsigned short* dst = q + ((size_t)n*HWX + p0 + pos)*CA + seg*32;
    float s2 = 0.f;
    #pragma unroll
    for (int u=0;u<4;u++) {
      short8 v = *(const short8*)(src + u*8);
      *(short8*)(dst + u*8) = v;
      half8 h = __builtin_bit_cast(half8, v);
      #pragma unroll
      for (int e=0;e<8;e++) { float fe = (float)h[e]; s2 += fe*fe; }
    }
    s2 += __shfl_xor(s2, 1, 64);
    s2 += __shfl_xor(s2, 2, 64);
    if (seg == 0) normq[(size_t)n*HWX + p0 + pos] = sqrtf(s2);
    float mx = s2;
    mx = fmaxf(mx, __shfl_xor(mx, 4, 64));
    mx = fmaxf(mx, __shfl_xor(mx, 8, 64));
    mx = fmaxf(mx, __shfl_xor(mx, 16, 64));
    mx = fmaxf(mx, __shfl_xor(mx, 32, 64));
    if (lane == 0) sGm[t >> 6] = sqrtf(mx);
  }
  __syncthreads();
  if (t == 0) {
    float m01 = fmaxf(sGm[0], sGm[1]);
    float m23 = fmaxf(sGm[2], sGm[3]);
    atomicMax(Gmax + n, __float_as_uint(fmaxf(m01, m23)));
  }
}

// ---------------- kernel 3: flash attention, BN=64, PV pipelined, 2ix4j QK ----------------
// R13 pipeline kept verbatim (fused phase1 = { PV(ji-1) || QK(ji) || SM(ji) };
// sP dbuf; stage isolated between barriers; 176.5us measured). R14 delta: QK wave
// decomposition (wq=w&3, wh=w>>2) -> (wiq=w&1, wjq=w>>1): each wave computes
// S[32 i x 16 j] as 2 chains SHARING each B-fragment. QK sQ reads halve
// (64 -> 32KB/block-iter; redundancy 4x -> 2x) -- the largest cuttable LDS-path
// term. QK MFMA count unchanged (8/wave); PV untouched. This is R6's idea at BN=64
// where it fits: ah 16->32 regs but bF is only 16 (K=64), peak live ~112 < 128 cap
// (R6 died at BN=128 with bF 32). sP store banks: quad stride 136B == 8 banks,
// 16 cols = 8 dword-pairs -> all 32 banks covered, col-pairs 2-way (free, m136).
// lrun/sL per j-quarter: sL[4][64], final l = sum of 4.
__global__ __launch_bounds__(512, 4) void flash_k(
    const unsigned short* __restrict__ q, const unsigned short* __restrict__ feat,
    const float* __restrict__ mask, const float* __restrict__ normq,
    const unsigned* __restrict__ Gmax, float* __restrict__ out) {
  __shared__ alignas(16) unsigned short sQ[64*128];     // j-tile q fp16, octet-swizzled
  __shared__ alignas(16) unsigned short sP[2][64][68];  // P dbuf (A-layout), pad 68
  __shared__ float sM[64];
  __shared__ float sL[4][64];
  int b = blockIdx.x;
  int n = b & 7, it = b >> 3;         // n == XCD for L2 locality
  int i0 = it * 64;
  int t = threadIdx.x;
  int w = t >> 6, lane = t & 63, quad = lane >> 4, col = lane & 15;
  int wiq = w & 1, wjq = w >> 1;      // QK: wiq = i-half (32 rows), wjq = j-quarter (16)
  const unsigned short* q_n = q + (size_t)n*HWX*CA;
  const unsigned short* f_n = feat + (size_t)n*CF*HWX;
  const float* m_n = mask + (size_t)n*HWX;
  const int rloc = t >> 4 & 31, oct16 = t & 15;
  const float inv_s = 1.0f/(1e-8f + sqrtf(128.0f));

  auto stage_Q = [&](int j0) {
    #pragma unroll
    for (int c=0;c<2;c++) {
      int row = c*32 + rloc;
      int og = oct16 ^ (row & 15);
      g2l16(q_n + (size_t)(j0+row)*CA + og*8, &sQ[(size_t)row*128 + oct16*8]);
    }
    if (t < 16) g2l16(m_n + j0 + t*4, &sM[t*4]);
  };

  // A fragments for QK (this wave's 32 i rows = 2 blocks of 16), resident all iters
  half8 ah[2][4];
  #pragma unroll
  for (int ip=0; ip<2; ip++) {
    int arow = i0 + wiq*32 + ip*16 + col;
    #pragma unroll
    for (int ks=0; ks<4; ks++)
      ah[ip][ks] = ld_half8(q_n + (size_t)arow*CA + ks*32 + quad*8);
  }
  // per-row exp shift: C_i - 5 (max-free softmax via Cauchy-Schwarz bound)
  float Gn = __uint_as_float(Gmax[n]);
  float cvals[2][4];
  #pragma unroll
  for (int ip=0;ip<2;ip++)
    #pragma unroll
    for (int r=0;r<4;r++)
      cvals[ip][r] = normq[(size_t)n*HWX + i0 + wiq*32 + ip*16 + quad*4 + r] * Gn * inv_s - 5.0f;

  f32x4 fzero = {0.f,0.f,0.f,0.f};
  f32x4 o[4][2];                      // [i-group][c-tile], PV c-slab = w*32
  #pragma unroll
  for (int ig=0;ig<4;ig++) { o[ig][0] = fzero; o[ig][1] = fzero; }
  float lrun[2][4] = {{0.f,0.f,0.f,0.f},{0.f,0.f,0.f,0.f}};

  // QK(ji)+SM(ji): S[32 i x 16 j]; each bq fragment feeds 2 MFMAs (ip=0,1)
  auto qk_sm = [&](int pc) {
    f32x4 s[2];
    s[0] = fzero; s[1] = fzero;
    int rowj = wjq*16 + col;
    #pragma unroll
    for (int ks=0; ks<4; ks++) {
      int slot = (ks*4 + quad) ^ (rowj & 15);
      half8 bq = ld_half8(&sQ[rowj*128 + slot*8]);
      #pragma unroll
      for (int ip=0;ip<2;ip++)
        s[ip] = __builtin_amdgcn_mfma_f32_16x16x32_f16(ah[ip][ks], bq, s[ip], 0, 0, 0);
    }
    float mj = (sM[wjq*16 + col] - 1.f) * 1e8f;
    #pragma unroll
    for (int ip=0;ip<2;ip++)
      #pragma unroll
      for (int r=0;r<4;r++) {
        float pv = __expf(s[ip][r]*inv_s + mj - cvals[ip][r]);
        lrun[ip][r] += pv;
        sP[pc][wiq*32 + ip*16 + quad*4 + r][wjq*16 + col] = f16_bits(pv);
      }
  };
  // PV of tile at base j0m, reading sP[pp] (unchanged from R13)
  auto pv = [&](int j0m, int pp) {
    half8 bF[2][2];
    #pragma unroll
    for (int ks2=0;ks2<2;ks2++)
      #pragma unroll
      for (int ct=0;ct<2;ct++) {
        int c = w*32 + ct*16 + col;
        bF[ks2][ct] = ld_half8(f_n + (size_t)c*HWX + j0m + ks2*32 + quad*8);
      }
    #pragma unroll
    for (int ks2=0; ks2<2; ks2++) {
      half8 aP[4];
      #pragma unroll
      for (int ig=0;ig<4;ig++) {
        const unsigned short* pp2 = &sP[pp][ig*16 + col][ks2*32 + quad*8];
        s16x4 lo = *(const s16x4*)pp2;       // rows 8B-aligned (136B stride)
        s16x4 hi = *(const s16x4*)(pp2 + 4);
        short8 vv = __builtin_shufflevector(lo, hi, 0,1,2,3,4,5,6,7);
        aP[ig] = __builtin_bit_cast(half8, vv);
      }
      #pragma unroll
      for (int ct=0;ct<2;ct++) {
        #pragma unroll
        for (int ig=0;ig<4;ig++)
          o[ig][ct] = __builtin_amdgcn_mfma_f32_16x16x32_f16(aP[ig], bF[ks2][ct], o[ig][ct], 0, 0, 0);
      }
    }
  };

  // ---- prologue: stage tile 0; peeled iter 0 (QK+SM only); stage tile 1
  stage_Q(0);
  __syncthreads();                    // tile 0 staged
  qk_sm(0);
  __syncthreads();                    // barrier B(0): sP[0] visible; sQ reads done
  stage_Q(64);
  __syncthreads();                    // barrier A: tile 1 staged

  // ---- main loop: fused phase1 = { PV(ji-1) || QK(ji) || SM(ji) }
  #pragma unroll 1
  for (int ji = 1; ji < 64; ji++) {
    int j0 = ji*64;
    __builtin_amdgcn_s_setprio(1);
    pv(j0 - 64, (ji-1) & 1);          // PV of previous tile from sP[(ji-1)&1]
    qk_sm(ji & 1);                    // QK+SM of current tile into sP[ji&1]
    __builtin_amdgcn_s_setprio(0);
    __syncthreads();                  // B: sP[ji&1] visible; sQ(ji) reads done
    if (ji < 63) stage_Q(j0 + 64);    // stage tile ji+1 (overwrites sQ safely)
    __syncthreads();                  // A: stage drained before QK(ji+1)
  }

  // ---- epilogue: PV of final tile 63 from sP[1]
  pv(63*64, 1);

  // ---- final l: reduce 16 j-cols in-wave (per quarter), combine 4 quarters via LDS
  #pragma unroll
  for (int ip=0;ip<2;ip++)
    #pragma unroll
    for (int r=0;r<4;r++) {
      float ss = lrun[ip][r];
      ss += __shfl_xor(ss, 1, 64);
      ss += __shfl_xor(ss, 2, 64);
      ss += __shfl_xor(ss, 4, 64);
      ss += __shfl_xor(ss, 8, 64);
      if (col == 0) sL[wjq][wiq*32 + ip*16 + quad*4 + r] = ss;
    }
  __syncthreads();
  #pragma unroll
  for (int ig=0;ig<4;ig++) {
    int base = ig*16 + quad*4;
    f32x4 l0 = *(const f32x4*)&sL[0][base];
    f32x4 l1 = *(const f32x4*)&sL[1][base];
    f32x4 l2 = *(const f32x4*)&sL[2][base];
    f32x4 l3 = *(const f32x4*)&sL[3][base];
    f32x4 mv = *(const f32x4*)(m_n + i0 + base);
    f32x4 minv;
    #pragma unroll
    for (int r=0;r<4;r++) minv[r] = mv[r] / (l0[r] + l1[r] + l2[r] + l3[r]);
    #pragma unroll
    for (int ct=0;ct<2;ct++) {
      int c = w*32 + ct*16 + col;
      f32x4 v;
      #pragma unroll
      for (int r=0;r<4;r++) v[r] = o[ig][ct][r] * minv[r];
      *(f32x4*)(out + ((size_t)n*CF + c)*HWX + i0 + base) = v;
    }
  }
}

extern "C" void kernel_launch(void* const* d_in, const int* in_sizes, int n_in,
                              void* d_out, int out_size, void* d_ws, size_t ws_size,
                              hipStream_t stream) {
  const float* x    = (const float*)d_in[0];
  const float* mask = (const float*)d_in[1];
  const float* rw   = (const float*)d_in[2];
  const float* rg   = (const float*)d_in[3];
  const float* rb   = (const float*)d_in[4];
  const float* rm   = (const float*)d_in[5];
  const float* rv   = (const float*)d_in[6];
  const float* aw   = (const float*)d_in[7];
  const float* ag   = (const float*)d_in[8];
  const float* ab   = (const float*)d_in[9];
  const float* am   = (const float*)d_in[10];
  const float* av   = (const float*)d_in[11];
  float* out = (float*)d_out;
  char* ws = (char*)d_ws;
  unsigned short* wh = (unsigned short*)(ws + OFF_WH);
  float* bias = (float*)(ws + OFF_BIAS);
  unsigned short* feat = (unsigned short*)(ws + OFF_FEAT);
  unsigned short* q    = (unsigned short*)(ws + OFF_Q);
  float* normq = (float*)(ws + OFF_NORM);
  unsigned* Gmax = (unsigned*)(ws + OFF_G);

  hipLaunchKernelGGL(fold_bn_k, dim3(CT), dim3(CIN), 0, stream,
                     rw, rg, rb, rm, rv, aw, ag, ab, am, av, wh, bias, Gmax);
  hipLaunchKernelGGL(conv_k, dim3(512), dim3(512), 0, stream,
                     x, wh, bias, feat, q, normq, Gmax);
  hipLaunchKernelGGL(flash_k, dim3(512), dim3(512), 0, stream,
                     q, feat, mask, normq, Gmax, out);
}

// Round 15
// 322.596 us; speedup vs baseline: 1.0817x; 1.0817x over previous
//
#include <hip/hip_runtime.h>
#include <cstdint>
#include <cstddef>

#define NB 8
#define CIN 256
#define HWX 4096
#define CF 256
#define CA 128
#define CT 384

typedef __attribute__((ext_vector_type(8))) _Float16 half8;
typedef __attribute__((ext_vector_type(8))) short short8;
typedef __attribute__((ext_vector_type(4))) short s16x4;
typedef __attribute__((ext_vector_type(4))) float f32x4;
typedef __attribute__((ext_vector_type(4))) unsigned int u32x4;
typedef __attribute__((ext_vector_type(2))) unsigned int u32x2;

// workspace layout (bytes)
#define OFF_WH   0                              // 384*256 fp16 folded weights
#define OFF_BIAS (CT*CIN*2)                     // 384 fp32 folded bias
#define OFF_FEAT (OFF_BIAS + CT*4)              // [n][256][4096] fp16
#define OFF_Q    (OFF_FEAT + NB*CF*HWX*2)       // [n][4096][128] fp16
#define OFF_NORM (OFF_Q + NB*HWX*CA*2)          // [n][4096] fp32 row norms of q
#define OFF_G    (OFF_NORM + NB*HWX*4)          // [n] uint (max norm bits)

__device__ inline unsigned short f16_bits(float f) {
  _Float16 h = (_Float16)f;
  return __builtin_bit_cast(unsigned short, h);
}
__device__ inline half8 ld_half8(const unsigned short* p) {
  short8 r = *(const short8*)p;
  return __builtin_bit_cast(half8, r);
}

// async global->LDS, 16B per lane; LDS side must be lane-linear (m104/m108),
// swizzle goes on the GLOBAL address.
__device__ inline void g2l16(const void* g, void* l) {
  __builtin_amdgcn_global_load_lds(
      (const __attribute__((address_space(1))) unsigned int*)g,
      (__attribute__((address_space(3))) unsigned int*)l, 16, 0, 0);
}

// ---------------- kernel 1: fold BN into fp16 weights (+ zero G) ----------------
__global__ __launch_bounds__(256) void fold_bn_k(
    const float* __restrict__ rw, const float* __restrict__ rg,
    const float* __restrict__ rb, const float* __restrict__ rm, const float* __restrict__ rv,
    const float* __restrict__ aw, const float* __restrict__ ag,
    const float* __restrict__ ab2, const float* __restrict__ am, const float* __restrict__ av,
    unsigned short* __restrict__ wh, float* __restrict__ bias, unsigned* __restrict__ Gmax) {
  int o = blockIdx.x, k = threadIdx.x;
  if (o == 0 && k < NB) Gmax[k] = 0u;
  const float* wsrc; float g, b, m, v;
  if (o < CF) { wsrc = rw + (size_t)o*CIN; g = rg[o]; b = rb[o]; m = rm[o]; v = rv[o]; }
  else { int oa = o - CF; wsrc = aw + (size_t)oa*CIN; g = ag[oa]; b = ab2[oa]; m = am[oa]; v = av[oa]; }
  float inv = g / sqrtf(v + 1e-5f);
  wh[(size_t)o*CIN + k] = f16_bits(wsrc[k] * inv);
  if (k == 0) bias[o] = b - m*inv;
}

// ---------------- kernel 2: fp16 MFMA conv(1x1)+BN+ReLU, 64-pos tiles ----------------
// EXACT R11 conv (banked best: residual 93-98us). R10 tile-halving (+8us) and R12
// oc-split occupancy (null) both exonerated occupancy as the conv limiter.
// grid 512 = 8n x 64 pos-tiles(64); 512 thr; 2 blocks/CU.
// B3 register-prefetch (R3, real); 1 atomic/block (R6, real: 111->93).
__global__ __launch_bounds__(512, 4) void conv_k(
    const float* __restrict__ x, const unsigned short* __restrict__ wh,
    const float* __restrict__ bias, unsigned short* __restrict__ feat,
    unsigned short* __restrict__ q, float* __restrict__ normq,
    unsigned* __restrict__ Gmax) {
  __shared__ unsigned short sX[64*256];   // xT [64 pos][256 k] fp16, swizzled; 32KB
  __shared__ float sGm[4];
  unsigned short (*sQr)[136] = (unsigned short(*)[136])sX;  // aliased after K-loop
  int b = blockIdx.x;
  int n = b & 7, pt0 = b >> 3;
  int p0 = pt0 * 64;
  int t = threadIdx.x;
  int w = t >> 6, lane = t & 63, quad = lane >> 4, col = lane & 15;
  const float* xn = x + (size_t)n*CIN*HWX;

  #pragma unroll
  for (int pass=0; pass<4; pass++) {
    int idx = pass*512 + t;
    int kp = idx >> 4, c4 = idx & 15;
    f32x4 a = *(const f32x4*)(xn + (size_t)(2*kp)*HWX + p0 + c4*4);
    f32x4 c = *(const f32x4*)(xn + (size_t)(2*kp+1)*HWX + p0 + c4*4);
    int unit = kp >> 2, off = kp & 3;
    #pragma unroll
    for (int j=0;j<4;j++) {
      int pos = c4*4 + j;
      unsigned dd = (unsigned)f16_bits(a[j]) | ((unsigned)f16_bits(c[j]) << 16);
      *(unsigned*)&sX[pos*256 + ((unit ^ (pos & 31)) << 3) + off*2] = dd;
    }
  }
  __syncthreads();

  f32x4 fzero = {0.f,0.f,0.f,0.f};
  f32x4 acc[4][3];
  #pragma unroll
  for (int pt=0;pt<4;pt++)
    #pragma unroll
    for (int ot=0;ot<3;ot++) acc[pt][ot] = fzero;

  int ocb = w*48;
  half8 B3[3];
  #pragma unroll
  for (int ot=0;ot<3;ot++)
    B3[ot] = ld_half8(wh + (size_t)(ocb + ot*16 + col)*CIN + quad*8);   // ks=0
  #pragma unroll
  for (int ks=0; ks<8; ks++) {
    half8 B3n[3];
    if (ks < 7) {
      #pragma unroll
      for (int ot=0;ot<3;ot++)
        B3n[ot] = ld_half8(wh + (size_t)(ocb + ot*16 + col)*CIN + (ks+1)*32 + quad*8);
    }
    half8 A4[4];
    #pragma unroll
    for (int pt=0;pt<4;pt++) {
      int pos = pt*16 + col;
      A4[pt] = ld_half8(&sX[pos*256 + (((ks*4 + quad) ^ (pos & 31)) << 3)]);
    }
    #pragma unroll
    for (int pt=0;pt<4;pt++)
      #pragma unroll
      for (int ot=0;ot<3;ot++)
        acc[pt][ot] = __builtin_amdgcn_mfma_f32_16x16x32_f16(A4[pt], B3[ot], acc[pt][ot], 0, 0, 0);
    if (ks < 7) {
      #pragma unroll
      for (int ot=0;ot<3;ot++) B3[ot] = B3n[ot];
    }
  }
  __syncthreads();   // all sX reads done; region reused as sQr

  float bv[3];
  #pragma unroll
  for (int ot=0;ot<3;ot++) bv[ot] = bias[ocb + ot*16 + col];
  #pragma unroll
  for (int pt=0;pt<4;pt++)
    #pragma unroll
    for (int ot=0;ot<3;ot++) {
      int oc = ocb + ot*16 + col;
      alignas(8) unsigned short u4[4];
      #pragma unroll
      for (int r=0;r<4;r++)
        u4[r] = f16_bits(fmaxf(acc[pt][ot][r] + bv[ot], 0.f));
      if (oc < CF) {
        *(u32x2*)(feat + (size_t)n*CF*HWX + (size_t)oc*HWX + p0 + pt*16 + quad*4) =
            *(const u32x2*)u4;
      } else {
        int cc = oc - CF;
        #pragma unroll
        for (int r=0;r<4;r++)
          sQr[pt*16 + quad*4 + r][cc] = u4[r];
      }
    }
  __syncthreads();

  if (t < 256) {
    int pos = t >> 2, seg = t & 3;
    const unsigned short* src = &sQr[pos][seg*32];
    unsigned short* dst = q + ((size_t)n*HWX + p0 + pos)*CA + seg*32;
    float s2 = 0.f;
    #pragma unroll
    for (int u=0;u<4;u++) {
      short8 v = *(const short8*)(src + u*8);
      *(short8*)(dst + u*8) = v;
      half8 h = __builtin_bit_cast(half8, v);
      #pragma unroll
      for (int e=0;e<8;e++) { float fe = (float)h[e]; s2 += fe*fe; }
    }
    s2 += __shfl_xor(s2, 1, 64);
    s2 += __shfl_xor(s2, 2, 64);
    if (seg == 0) normq[(size_t)n*HWX + p0 + pos] = sqrtf(s2);
    float mx = s2;
    mx = fmaxf(mx, __shfl_xor(mx, 4, 64));
    mx = fmaxf(mx, __shfl_xor(mx, 8, 64));
    mx = fmaxf(mx, __shfl_xor(mx, 16, 64));
    mx = fmaxf(mx, __shfl_xor(mx, 32, 64));
    if (lane == 0) sGm[t >> 6] = sqrtf(mx);
  }
  __syncthreads();
  if (t == 0) {
    float m01 = fmaxf(sGm[0], sGm[1]);
    float m23 = fmaxf(sGm[2], sGm[3]);
    atomicMax(Gmax + n, __float_as_uint(fmaxf(m01, m23)));
  }
}

// ---------------- kernel 3: flash attention, BN=64, fused pipeline, ONE barrier/iter ----------------
// R15 = R13's fusion (phase = { stage(ji+1) || PV(ji-1) || QK(ji) || SM(ji) }) with
// sQ/sM double-buffered (NAMED buffers + 2x-unrolled pairs -- compile-time LDS bases,
// R8 lesson) so the stage no longer needs its own barrier: 64 barriers/block vs
// R13's 128. NOT R9 (which lacked fusion; its wave chain QK->SM->bar->PV stayed
// serial). QK decomposition reverted to R13's (wq=w&3, wh=w>>2) -- R14's B-sharing
// split spilled (FETCH +9MB scratch, MfmaUtil 24.6->16.9; 3rd reg-cliff occurrence).
// Hazards (each writer/next-reader pair separated by exactly one barrier):
//   stage(ji+1)->sQ[(ji+1)&1] concurrent with QK(ji) on sQ[ji&1] (disjoint);
//   QK(ji+1) reads it after barrier(ji) (implicit vmcnt(0) drains g2l16);
//   SM(ji)->sP[ji&1] disjoint from PV(ji-1)'s sP[(ji-1)&1]; PV(ji) reads after
//   barrier(ji); SM(ji+2) overwrites after barrier(ji+1) > PV(ji).
// Registers == R13 (~60, no new persistent state). LDS 51.2KB -> 2 blocks/CU.
__global__ __launch_bounds__(512, 4) void flash_k(
    const unsigned short* __restrict__ q, const unsigned short* __restrict__ feat,
    const float* __restrict__ mask, const float* __restrict__ normq,
    const unsigned* __restrict__ Gmax, float* __restrict__ out) {
  __shared__ alignas(16) unsigned short sQ0[64*128];    // j-tile q fp16, octet-swizzled
  __shared__ alignas(16) unsigned short sQ1[64*128];
  __shared__ alignas(16) unsigned short sP0[64][68];    // P (A-layout), pad 68
  __shared__ alignas(16) unsigned short sP1[64][68];
  __shared__ float sM0[64];
  __shared__ float sM1[64];
  __shared__ float sL[2][64];
  int b = blockIdx.x;
  int n = b & 7, it = b >> 3;         // n == XCD for L2 locality
  int i0 = it * 64;
  int t = threadIdx.x;
  int w = t >> 6, lane = t & 63, quad = lane >> 4, col = lane & 15;
  int wq = w & 3, wh = w >> 2;        // QK: wq = i-16-block, wh = j-32-half
  const unsigned short* q_n = q + (size_t)n*HWX*CA;
  const unsigned short* f_n = feat + (size_t)n*CF*HWX;
  const float* m_n = mask + (size_t)n*HWX;
  const int rloc = t >> 4 & 31, oct16 = t & 15;
  const float inv_s = 1.0f/(1e-8f + sqrtf(128.0f));

  auto stage_Q = [&](int j0, unsigned short* sQd, float* sMd) {
    #pragma unroll
    for (int c=0;c<2;c++) {
      int row = c*32 + rloc;
      int og = oct16 ^ (row & 15);
      g2l16(q_n + (size_t)(j0+row)*CA + og*8, &sQd[(size_t)row*128 + oct16*8]);
    }
    if (t < 16) g2l16(m_n + j0 + t*4, &sMd[t*4]);
  };

  // A fragments for QK (this wave's 16 i rows), resident all iters
  half8 ah[4];
  {
    int arow = i0 + wq*16 + col;
    #pragma unroll
    for (int ks=0; ks<4; ks++)
      ah[ks] = ld_half8(q_n + (size_t)arow*CA + ks*32 + quad*8);
  }
  // per-row exp shift: C_i - 5 (max-free softmax via Cauchy-Schwarz bound)
  float Gn = __uint_as_float(Gmax[n]);
  float cvals[4];
  #pragma unroll
  for (int r=0;r<4;r++)
    cvals[r] = normq[(size_t)n*HWX + i0 + wq*16 + quad*4 + r] * Gn * inv_s - 5.0f;

  f32x4 fzero = {0.f,0.f,0.f,0.f};
  f32x4 o[4][2];                      // [i-group][c-tile], PV c-slab = w*32
  #pragma unroll
  for (int ig=0;ig<4;ig++) { o[ig][0] = fzero; o[ig][1] = fzero; }
  float lrun[4] = {0.f,0.f,0.f,0.f};

  // QK(ji)+SM(ji): S[16 i x 32 j], 2 indep chains of 4 (R13 decomposition)
  auto qk_sm = [&](const unsigned short* sQc, const float* sMc,
                   unsigned short (*sPc)[68]) {
    f32x4 s[2];
    s[0] = fzero; s[1] = fzero;
    #pragma unroll
    for (int jt=0;jt<2;jt++) {
      int rowj = wh*32 + jt*16 + col;
      #pragma unroll
      for (int ks=0; ks<4; ks++) {
        int slot = (ks*4 + quad) ^ (rowj & 15);
        half8 bq = ld_half8(&sQc[rowj*128 + slot*8]);
        s[jt] = __builtin_amdgcn_mfma_f32_16x16x32_f16(ah[ks], bq, s[jt], 0, 0, 0);
      }
    }
    #pragma unroll
    for (int jt=0;jt<2;jt++) {
      float mj = (sMc[wh*32 + jt*16 + col] - 1.f) * 1e8f;
      #pragma unroll
      for (int r=0;r<4;r++) {
        float pv = __expf(s[jt][r]*inv_s + mj - cvals[r]);
        lrun[r] += pv;
        sPc[wq*16 + quad*4 + r][wh*32 + jt*16 + col] = f16_bits(pv);
      }
    }
  };
  // PV of tile at base j0m, reading sPc (R13 verbatim)
  auto pv_f = [&](int j0m, unsigned short (*sPc)[68]) {
    half8 bF[2][2];
    #pragma unroll
    for (int ks2=0;ks2<2;ks2++)
      #pragma unroll
      for (int ct=0;ct<2;ct++) {
        int c = w*32 + ct*16 + col;
        bF[ks2][ct] = ld_half8(f_n + (size_t)c*HWX + j0m + ks2*32 + quad*8);
      }
    #pragma unroll
    for (int ks2=0; ks2<2; ks2++) {
      half8 aP[4];
      #pragma unroll
      for (int ig=0;ig<4;ig++) {
        const unsigned short* pp2 = &sPc[ig*16 + col][ks2*32 + quad*8];
        s16x4 lo = *(const s16x4*)pp2;       // rows 8B-aligned (136B stride)
        s16x4 hi = *(const s16x4*)(pp2 + 4);
        short8 vv = __builtin_shufflevector(lo, hi, 0,1,2,3,4,5,6,7);
        aP[ig] = __builtin_bit_cast(half8, vv);
      }
      #pragma unroll
      for (int ct=0;ct<2;ct++) {
        #pragma unroll
        for (int ig=0;ig<4;ig++)
          o[ig][ct] = __builtin_amdgcn_mfma_f32_16x16x32_f16(aP[ig], bF[ks2][ct], o[ig][ct], 0, 0, 0);
      }
    }
  };

  // ---- prologue
  stage_Q(0, sQ0, sM0);
  __syncthreads();                    // tile 0 staged
  // phase(0): stage tile 1 || QK+SM(0)
  stage_Q(64, sQ1, sM1);
  qk_sm(sQ0, sM0, sP0);
  __syncthreads();                    // bar(0): sP0 + sQ1 ready

  // ---- main loop: ji = 1..62 as 31 unrolled pairs (compile-time LDS bases)
  #pragma unroll 1
  for (int jj = 0; jj < 31; jj++) {
    int ji = 2*jj + 1;
    // phase(ji) odd: stage(ji+1)->sQ0; PV(ji-1)<-sP0; QK+SM(ji) sQ1->sP1
    stage_Q((ji+1)*64, sQ0, sM0);
    __builtin_amdgcn_s_setprio(1);
    pv_f((ji-1)*64, sP0);
    qk_sm(sQ1, sM1, sP1);
    __builtin_amdgcn_s_setprio(0);
    __syncthreads();                  // bar(ji)
    // phase(ji+1) even: stage(ji+2)->sQ1; PV(ji)<-sP1; QK+SM(ji+1) sQ0->sP0
    stage_Q((ji+2)*64, sQ1, sM1);
    __builtin_amdgcn_s_setprio(1);
    pv_f(ji*64, sP1);
    qk_sm(sQ0, sM0, sP0);
    __builtin_amdgcn_s_setprio(0);
    __syncthreads();                  // bar(ji+1)
  }

  // ---- phase(63): no stage; PV(62)<-sP0; QK+SM(63) sQ1->sP1
  __builtin_amdgcn_s_setprio(1);
  pv_f(62*64, sP0);
  qk_sm(sQ1, sM1, sP1);
  __builtin_amdgcn_s_setprio(0);
  __syncthreads();                    // bar(63): sP1 visible

  // ---- epilogue: PV of final tile 63
  pv_f(63*64, sP1);

  // ---- final l: reduce 16 j-cols in-wave, combine the 2 j-halves via LDS
  #pragma unroll
  for (int r=0;r<4;r++) {
    float ss = lrun[r];
    ss += __shfl_xor(ss, 1, 64);
    ss += __shfl_xor(ss, 2, 64);
    ss += __shfl_xor(ss, 4, 64);
    ss += __shfl_xor(ss, 8, 64);
    lrun[r] = ss;
  }
  #pragma unroll
  for (int r=0;r<4;r++)
    if (col == 0) sL[wh][wq*16 + quad*4 + r] = lrun[r];
  __syncthreads();
  #pragma unroll
  for (int ig=0;ig<4;ig++) {
    int base = ig*16 + quad*4;
    f32x4 l0 = *(const f32x4*)&sL[0][base];
    f32x4 l1 = *(const f32x4*)&sL[1][base];
    f32x4 mv = *(const f32x4*)(m_n + i0 + base);
    f32x4 minv;
    #pragma unroll
    for (int r=0;r<4;r++) minv[r] = mv[r] / (l0[r] + l1[r]);
    #pragma unroll
    for (int ct=0;ct<2;ct++) {
      int c = w*32 + ct*16 + col;
      f32x4 v;
      #pragma unroll
      for (int r=0;r<4;r++) v[r] = o[ig][ct][r] * minv[r];
      *(f32x4*)(out + ((size_t)n*CF + c)*HWX + i0 + base) = v;
    }
  }
}

extern "C" void kernel_launch(void* const* d_in, const int* in_sizes, int n_in,
                              void* d_out, int out_size, void* d_ws, size_t ws_size,
                              hipStream_t stream) {
  const float* x    = (const float*)d_in[0];
  const float* mask = (const float*)d_in[1];
  const float* rw   = (const float*)d_in[2];
  const float* rg   = (const float*)d_in[3];
  const float* rb   = (const float*)d_in[4];
  const float* rm   = (const float*)d_in[5];
  const float* rv   = (const float*)d_in[6];
  const float* aw   = (const float*)d_in[7];
  const float* ag   = (const float*)d_in[8];
  const float* ab   = (const float*)d_in[9];
  const float* am   = (const float*)d_in[10];
  const float* av   = (const float*)d_in[11];
  float* out = (float*)d_out;
  char* ws = (char*)d_ws;
  unsigned short* wh = (unsigned short*)(ws + OFF_WH);
  float* bias = (float*)(ws + OFF_BIAS);
  unsigned short* feat = (unsigned short*)(ws + OFF_FEAT);
  unsigned short* q    = (unsigned short*)(ws + OFF_Q);
  float* normq = (float*)(ws + OFF_NORM);
  unsigned* Gmax = (unsigned*)(ws + OFF_G);

  hipLaunchKernelGGL(fold_bn_k, dim3(CT), dim3(CIN), 0, stream,
                     rw, rg, rb, rm, rv, aw, ag, ab, am, av, wh, bias, Gmax);
  hipLaunchKernelGGL(conv_k, dim3(512), dim3(512), 0, stream,
                     x, wh, bias, feat, q, normq, Gmax);
  hipLaunchKernelGGL(flash_k, dim3(512), dim3(512), 0, stream,
                     q, feat, mask, normq, Gmax, out);
}

// Round 16
// 274.578 us; speedup vs baseline: 1.2709x; 1.1749x over previous
//
#include <hip/hip_runtime.h>
#include <cstdint>
#include <cstddef>

#define NB 8
#define CIN 256
#define HWX 4096
#define CF 256
#define CA 128
#define CT 384

typedef __attribute__((ext_vector_type(8))) _Float16 half8;
typedef __attribute__((ext_vector_type(8))) short short8;
typedef __attribute__((ext_vector_type(4))) short s16x4;
typedef __attribute__((ext_vector_type(4))) float f32x4;
typedef __attribute__((ext_vector_type(4))) unsigned int u32x4;
typedef __attribute__((ext_vector_type(2))) unsigned int u32x2;

// workspace layout (bytes)
#define OFF_WH   0                              // 384*256 fp16 folded weights
#define OFF_BIAS (CT*CIN*2)                     // 384 fp32 folded bias
#define OFF_FEAT (OFF_BIAS + CT*4)              // [n][256][4096] fp16
#define OFF_Q    (OFF_FEAT + NB*CF*HWX*2)       // [n][4096][128] fp16
#define OFF_NORM (OFF_Q + NB*HWX*CA*2)          // [n][4096] fp32 row norms of q
#define OFF_G    (OFF_NORM + NB*HWX*4)          // [n] uint (max norm bits)

__device__ inline unsigned short f16_bits(float f) {
  _Float16 h = (_Float16)f;
  return __builtin_bit_cast(unsigned short, h);
}
__device__ inline half8 ld_half8(const unsigned short* p) {
  short8 r = *(const short8*)p;
  return __builtin_bit_cast(half8, r);
}

// async global->LDS, 16B per lane; LDS side must be lane-linear (m104/m108),
// swizzle goes on the GLOBAL address.
__device__ inline void g2l16(const void* g, void* l) {
  __builtin_amdgcn_global_load_lds(
      (const __attribute__((address_space(1))) unsigned int*)g,
      (__attribute__((address_space(3))) unsigned int*)l, 16, 0, 0);
}

// ---------------- kernel 1: fold BN into fp16 weights (+ zero G) ----------------
__global__ __launch_bounds__(256) void fold_bn_k(
    const float* __restrict__ rw, const float* __restrict__ rg,
    const float* __restrict__ rb, const float* __restrict__ rm, const float* __restrict__ rv,
    const float* __restrict__ aw, const float* __restrict__ ag,
    const float* __restrict__ ab2, const float* __restrict__ am, const float* __restrict__ av,
    unsigned short* __restrict__ wh, float* __restrict__ bias, unsigned* __restrict__ Gmax) {
  int o = blockIdx.x, k = threadIdx.x;
  if (o == 0 && k < NB) Gmax[k] = 0u;
  const float* wsrc; float g, b, m, v;
  if (o < CF) { wsrc = rw + (size_t)o*CIN; g = rg[o]; b = rb[o]; m = rm[o]; v = rv[o]; }
  else { int oa = o - CF; wsrc = aw + (size_t)oa*CIN; g = ag[oa]; b = ab2[oa]; m = am[oa]; v = av[oa]; }
  float inv = g / sqrtf(v + 1e-5f);
  wh[(size_t)o*CIN + k] = f16_bits(wsrc[k] * inv);
  if (k == 0) bias[o] = b - m*inv;
}

// ---------------- kernel 2: fp16 MFMA conv(1x1)+BN+ReLU, 64-pos tiles ----------------
// EXACT R11 conv (banked best: residual 93-98us). R10 tile-halving (+8us) and R12
// oc-split occupancy (null) both exonerated occupancy as the conv limiter.
// grid 512 = 8n x 64 pos-tiles(64); 512 thr; 2 blocks/CU.
// B3 register-prefetch (R3, real); 1 atomic/block (R6, real: 111->93).
__global__ __launch_bounds__(512, 4) void conv_k(
    const float* __restrict__ x, const unsigned short* __restrict__ wh,
    const float* __restrict__ bias, unsigned short* __restrict__ feat,
    unsigned short* __restrict__ q, float* __restrict__ normq,
    unsigned* __restrict__ Gmax) {
  __shared__ unsigned short sX[64*256];   // xT [64 pos][256 k] fp16, swizzled; 32KB
  __shared__ float sGm[4];
  unsigned short (*sQr)[136] = (unsigned short(*)[136])sX;  // aliased after K-loop
  int b = blockIdx.x;
  int n = b & 7, pt0 = b >> 3;
  int p0 = pt0 * 64;
  int t = threadIdx.x;
  int w = t >> 6, lane = t & 63, quad = lane >> 4, col = lane & 15;
  const float* xn = x + (size_t)n*CIN*HWX;

  #pragma unroll
  for (int pass=0; pass<4; pass++) {
    int idx = pass*512 + t;
    int kp = idx >> 4, c4 = idx & 15;
    f32x4 a = *(const f32x4*)(xn + (size_t)(2*kp)*HWX + p0 + c4*4);
    f32x4 c = *(const f32x4*)(xn + (size_t)(2*kp+1)*HWX + p0 + c4*4);
    int unit = kp >> 2, off = kp & 3;
    #pragma unroll
    for (int j=0;j<4;j++) {
      int pos = c4*4 + j;
      unsigned dd = (unsigned)f16_bits(a[j]) | ((unsigned)f16_bits(c[j]) << 16);
      *(unsigned*)&sX[pos*256 + ((unit ^ (pos & 31)) << 3) + off*2] = dd;
    }
  }
  __syncthreads();

  f32x4 fzero = {0.f,0.f,0.f,0.f};
  f32x4 acc[4][3];
  #pragma unroll
  for (int pt=0;pt<4;pt++)
    #pragma unroll
    for (int ot=0;ot<3;ot++) acc[pt][ot] = fzero;

  int ocb = w*48;
  half8 B3[3];
  #pragma unroll
  for (int ot=0;ot<3;ot++)
    B3[ot] = ld_half8(wh + (size_t)(ocb + ot*16 + col)*CIN + quad*8);   // ks=0
  #pragma unroll
  for (int ks=0; ks<8; ks++) {
    half8 B3n[3];
    if (ks < 7) {
      #pragma unroll
      for (int ot=0;ot<3;ot++)
        B3n[ot] = ld_half8(wh + (size_t)(ocb + ot*16 + col)*CIN + (ks+1)*32 + quad*8);
    }
    half8 A4[4];
    #pragma unroll
    for (int pt=0;pt<4;pt++) {
      int pos = pt*16 + col;
      A4[pt] = ld_half8(&sX[pos*256 + (((ks*4 + quad) ^ (pos & 31)) << 3)]);
    }
    #pragma unroll
    for (int pt=0;pt<4;pt++)
      #pragma unroll
      for (int ot=0;ot<3;ot++)
        acc[pt][ot] = __builtin_amdgcn_mfma_f32_16x16x32_f16(A4[pt], B3[ot], acc[pt][ot], 0, 0, 0);
    if (ks < 7) {
      #pragma unroll
      for (int ot=0;ot<3;ot++) B3[ot] = B3n[ot];
    }
  }
  __syncthreads();   // all sX reads done; region reused as sQr

  float bv[3];
  #pragma unroll
  for (int ot=0;ot<3;ot++) bv[ot] = bias[ocb + ot*16 + col];
  #pragma unroll
  for (int pt=0;pt<4;pt++)
    #pragma unroll
    for (int ot=0;ot<3;ot++) {
      int oc = ocb + ot*16 + col;
      alignas(8) unsigned short u4[4];
      #pragma unroll
      for (int r=0;r<4;r++)
        u4[r] = f16_bits(fmaxf(acc[pt][ot][r] + bv[ot], 0.f));
      if (oc < CF) {
        *(u32x2*)(feat + (size_t)n*CF*HWX + (size_t)oc*HWX + p0 + pt*16 + quad*4) =
            *(const u32x2*)u4;
      } else {
        int cc = oc - CF;
        #pragma unroll
        for (int r=0;r<4;r++)
          sQr[pt*16 + quad*4 + r][cc] = u4[r];
      }
    }
  __syncthreads();

  if (t < 256) {
    int pos = t >> 2, seg = t & 3;
    const unsigned short* src = &sQr[pos][seg*32];
    unsigned short* dst = q + ((size_t)n*HWX + p0 + pos)*CA + seg*32;
    float s2 = 0.f;
    #pragma unroll
    for (int u=0;u<4;u++) {
      short8 v = *(const short8*)(src + u*8);
      *(short8*)(dst + u*8) = v;
      half8 h = __builtin_bit_cast(half8, v);
      #pragma unroll
      for (int e=0;e<8;e++) { float fe = (float)h[e]; s2 += fe*fe; }
    }
    s2 += __shfl_xor(s2, 1, 64);
    s2 += __shfl_xor(s2, 2, 64);
    if (seg == 0) normq[(size_t)n*HWX + p0 + pos] = sqrtf(s2);
    float mx = s2;
    mx = fmaxf(mx, __shfl_xor(mx, 4, 64));
    mx = fmaxf(mx, __shfl_xor(mx, 8, 64));
    mx = fmaxf(mx, __shfl_xor(mx, 16, 64));
    mx = fmaxf(mx, __shfl_xor(mx, 32, 64));
    if (lane == 0) sGm[t >> 6] = sqrtf(mx);
  }
  __syncthreads();
  if (t == 0) {
    float m01 = fmaxf(sGm[0], sGm[1]);
    float m23 = fmaxf(sGm[2], sGm[3]);
    atomicMax(Gmax + n, __float_as_uint(fmaxf(m01, m23)));
  }
}

// ---------------- kernel 3: flash attention, BN=64, PV pipelined 1 iter behind ----------------
// EXACT R13 kernel (measured 176.5us; session-best total 275.3). Fused phase1 =
// { bF loads + PV(ji-1) + QK(ji) + SM(ji) } in one branch-free region: the
// INDEPENDENT PV(ji-1) MFMAs fill QK's dependent-chain and SM's VALU latency.
// sP double-buffered [2][64][68] (conflict-free verified); sQ/sM single-buffered
// with stage isolated between the two barriers. Post-R13 variants all regressed:
// R14 QK-split (silent spill, -44%), R15 one-barrier dbuf (spill, -29%).
// VGPR 60, FETCH 12.5MB, conflicts 0 measured.
__global__ __launch_bounds__(512, 4) void flash_k(
    const unsigned short* __restrict__ q, const unsigned short* __restrict__ feat,
    const float* __restrict__ mask, const float* __restrict__ normq,
    const unsigned* __restrict__ Gmax, float* __restrict__ out) {
  __shared__ alignas(16) unsigned short sQ[64*128];     // j-tile q fp16, octet-swizzled
  __shared__ alignas(16) unsigned short sP[2][64][68];  // P dbuf (A-layout), pad 68
  __shared__ float sM[64];
  __shared__ float sL[2][64];
  int b = blockIdx.x;
  int n = b & 7, it = b >> 3;         // n == XCD for L2 locality
  int i0 = it * 64;
  int t = threadIdx.x;
  int w = t >> 6, lane = t & 63, quad = lane >> 4, col = lane & 15;
  int wq = w & 3, wh = w >> 2;        // QK: wq = i-16-block, wh = j-32-half
  const unsigned short* q_n = q + (size_t)n*HWX*CA;
  const unsigned short* f_n = feat + (size_t)n*CF*HWX;
  const float* m_n = mask + (size_t)n*HWX;
  const int rloc = t >> 4 & 31, oct16 = t & 15;
  const float inv_s = 1.0f/(1e-8f + sqrtf(128.0f));

  auto stage_Q = [&](int j0) {
    #pragma unroll
    for (int c=0;c<2;c++) {
      int row = c*32 + rloc;
      int og = oct16 ^ (row & 15);
      g2l16(q_n + (size_t)(j0+row)*CA + og*8, &sQ[(size_t)row*128 + oct16*8]);
    }
    if (t < 16) g2l16(m_n + j0 + t*4, &sM[t*4]);
  };

  // A fragments for QK (this wave's 16 i rows), resident all iters
  half8 ah[4];
  {
    int arow = i0 + wq*16 + col;
    #pragma unroll
    for (int ks=0; ks<4; ks++)
      ah[ks] = ld_half8(q_n + (size_t)arow*CA + ks*32 + quad*8);
  }
  // per-row exp shift: C_i - 5 (max-free softmax via Cauchy-Schwarz bound)
  float Gn = __uint_as_float(Gmax[n]);
  float cvals[4];
  #pragma unroll
  for (int r=0;r<4;r++)
    cvals[r] = normq[(size_t)n*HWX + i0 + wq*16 + quad*4 + r] * Gn * inv_s - 5.0f;

  f32x4 fzero = {0.f,0.f,0.f,0.f};
  f32x4 o[4][2];                      // [i-group][c-tile], PV c-slab = w*32
  #pragma unroll
  for (int ig=0;ig<4;ig++) { o[ig][0] = fzero; o[ig][1] = fzero; }
  float lrun[4] = {0.f,0.f,0.f,0.f};

  // QK(ji)+SM(ji) as a reusable block
  auto qk_sm = [&](int pc) {
    f32x4 s[2];
    s[0] = fzero; s[1] = fzero;
    #pragma unroll
    for (int jt=0;jt<2;jt++) {
      int rowj = wh*32 + jt*16 + col;
      #pragma unroll
      for (int ks=0; ks<4; ks++) {
        int slot = (ks*4 + quad) ^ (rowj & 15);
        half8 bq = ld_half8(&sQ[rowj*128 + slot*8]);
        s[jt] = __builtin_amdgcn_mfma_f32_16x16x32_f16(ah[ks], bq, s[jt], 0, 0, 0);
      }
    }
    #pragma unroll
    for (int jt=0;jt<2;jt++) {
      float mj = (sM[wh*32 + jt*16 + col] - 1.f) * 1e8f;
      #pragma unroll
      for (int r=0;r<4;r++) {
        float pv = __expf(s[jt][r]*inv_s + mj - cvals[r]);
        lrun[r] += pv;
        sP[pc][wq*16 + quad*4 + r][wh*32 + jt*16 + col] = f16_bits(pv);
      }
    }
  };
  // PV of tile at base j0m, reading sP[pp]
  auto pv = [&](int j0m, int pp) {
    half8 bF[2][2];
    #pragma unroll
    for (int ks2=0;ks2<2;ks2++)
      #pragma unroll
      for (int ct=0;ct<2;ct++) {
        int c = w*32 + ct*16 + col;
        bF[ks2][ct] = ld_half8(f_n + (size_t)c*HWX + j0m + ks2*32 + quad*8);
      }
    #pragma unroll
    for (int ks2=0; ks2<2; ks2++) {
      half8 aP[4];
      #pragma unroll
      for (int ig=0;ig<4;ig++) {
        const unsigned short* pp2 = &sP[pp][ig*16 + col][ks2*32 + quad*8];
        s16x4 lo = *(const s16x4*)pp2;       // rows 8B-aligned (136B stride)
        s16x4 hi = *(const s16x4*)(pp2 + 4);
        short8 vv = __builtin_shufflevector(lo, hi, 0,1,2,3,4,5,6,7);
        aP[ig] = __builtin_bit_cast(half8, vv);
      }
      #pragma unroll
      for (int ct=0;ct<2;ct++) {
        #pragma unroll
        for (int ig=0;ig<4;ig++)
          o[ig][ct] = __builtin_amdgcn_mfma_f32_16x16x32_f16(aP[ig], bF[ks2][ct], o[ig][ct], 0, 0, 0);
      }
    }
  };

  // ---- prologue: stage tile 0; peeled iter 0 (QK+SM only); stage tile 1
  stage_Q(0);
  __syncthreads();                    // tile 0 staged
  qk_sm(0);
  __syncthreads();                    // barrier B(0): sP[0] visible; sQ reads done
  stage_Q(64);
  __syncthreads();                    // barrier A: tile 1 staged

  // ---- main loop: fused phase1 = { PV(ji-1) || QK(ji) || SM(ji) }
  #pragma unroll 1
  for (int ji = 1; ji < 64; ji++) {
    int j0 = ji*64;
    __builtin_amdgcn_s_setprio(1);
    pv(j0 - 64, (ji-1) & 1);          // PV of previous tile from sP[(ji-1)&1]
    qk_sm(ji & 1);                    // QK+SM of current tile into sP[ji&1]
    __builtin_amdgcn_s_setprio(0);
    __syncthreads();                  // B: sP[ji&1] visible; sQ(ji) reads done
    if (ji < 63) stage_Q(j0 + 64);    // stage tile ji+1 (overwrites sQ safely)
    __syncthreads();                  // A: stage drained before QK(ji+1)
  }

  // ---- epilogue: PV of final tile 63 from sP[1]
  pv(63*64, 1);

  // ---- final l: reduce 16 j-cols in-wave, combine the 2 j-halves via LDS
  #pragma unroll
  for (int r=0;r<4;r++) {
    float ss = lrun[r];
    ss += __shfl_xor(ss, 1, 64);
    ss += __shfl_xor(ss, 2, 64);
    ss += __shfl_xor(ss, 4, 64);
    ss += __shfl_xor(ss, 8, 64);
    lrun[r] = ss;
  }
  #pragma unroll
  for (int r=0;r<4;r++)
    if (col == 0) sL[wh][wq*16 + quad*4 + r] = lrun[r];
  __syncthreads();
  #pragma unroll
  for (int ig=0;ig<4;ig++) {
    int base = ig*16 + quad*4;
    f32x4 l0 = *(const f32x4*)&sL[0][base];
    f32x4 l1 = *(const f32x4*)&sL[1][base];
    f32x4 mv = *(const f32x4*)(m_n + i0 + base);
    f32x4 minv;
    #pragma unroll
    for (int r=0;r<4;r++) minv[r] = mv[r] / (l0[r] + l1[r]);
    #pragma unroll
    for (int ct=0;ct<2;ct++) {
      int c = w*32 + ct*16 + col;
      f32x4 v;
      #pragma unroll
      for (int r=0;r<4;r++) v[r] = o[ig][ct][r] * minv[r];
      *(f32x4*)(out + ((size_t)n*CF + c)*HWX + i0 + base) = v;
    }
  }
}

extern "C" void kernel_launch(void* const* d_in, const int* in_sizes, int n_in,
                              void* d_out, int out_size, void* d_ws, size_t ws_size,
                              hipStream_t stream) {
  const float* x    = (const float*)d_in[0];
  const float* mask = (const float*)d_in[1];
  const float* rw   = (const float*)d_in[2];
  const float* rg   = (const float*)d_in[3];
  const float* rb   = (const float*)d_in[4];
  const float* rm   = (const float*)d_in[5];
  const float* rv   = (const float*)d_in[6];
  const float* aw   = (const float*)d_in[7];
  const float* ag   = (const float*)d_in[8];
  const float* ab   = (const float*)d_in[9];
  const float* am   = (const float*)d_in[10];
  const float* av   = (const float*)d_in[11];
  float* out = (float*)d_out;
  char* ws = (char*)d_ws;
  unsigned short* wh = (unsigned short*)(ws + OFF_WH);
  float* bias = (float*)(ws + OFF_BIAS);
  unsigned short* feat = (unsigned short*)(ws + OFF_FEAT);
  unsigned short* q    = (unsigned short*)(ws + OFF_Q);
  float* normq = (float*)(ws + OFF_NORM);
  unsigned* Gmax = (unsigned*)(ws + OFF_G);

  hipLaunchKernelGGL(fold_bn_k, dim3(CT), dim3(CIN), 0, stream,
                     rw, rg, rb, rm, rv, aw, ag, ab, am, av, wh, bias, Gmax);
  hipLaunchKernelGGL(conv_k, dim3(512), dim3(512), 0, stream,
                     x, wh, bias, feat, q, normq, Gmax);
  hipLaunchKernelGGL(flash_k, dim3(512), dim3(512), 0, stream,
                     q, feat, mask, normq, Gmax, out);
}